// Round 2
// baseline (21497.160 us; speedup 1.0000x reference)
//
#include <hip/hip_runtime.h>

// ---------------- problem constants ----------------
#define BB   32
#define SS   512
#define DD   256
#define HH   8
#define HDIM 64
#define NLAYER 5
#define FFD  1024
#define OUTD 4096
#define QN   512            // H*HD
#define BS   (BB*SS)        // 16384 tokens

// ---------------- embedding + positional encoding ----------------
// grid = BS blocks, 256 threads (one per dim)
__global__ __launch_bounds__(256) void embed_pe_kernel(
        const int* __restrict__ x, const float* __restrict__ emb,
        float* __restrict__ h) {
    int t = blockIdx.x;            // token index b*S + s
    int d = threadIdx.x;           // 0..255
    int pos = t % SS;
    int tok = x[t];
    float e = emb[(size_t)tok * DD + d];
    // div = 10000^((d&~1)/D); ang = pos/div
    float expo = -(float)(d & ~1) / (float)DD;
    float ang = (float)pos * powf(10000.0f, expo);
    float pe = (d & 1) ? cosf(ang) : sinf(ang);
    h[(size_t)t * DD + d] = e + pe;
}

// ---------------- generic tiled GEMM ----------------
// C[M,N] = A[M,K] * W[K,N] + bias[N], optional relu. All f32.
// BM=BN=64, BK=16, 256 threads, 4x4 microtile per thread.
// Requires M%64==0, N%64==0, K%16==0.
template<bool RELU>
__global__ __launch_bounds__(256) void gemm64_kernel(
        const float* __restrict__ A, const float* __restrict__ W,
        const float* __restrict__ bias, float* __restrict__ C,
        int M, int N, int K) {
    __shared__ float sA[16][65];
    __shared__ float sB[16][68];

    const int tid = threadIdx.x;
    const int tx = tid & 15;        // 0..15 -> n
    const int ty = tid >> 4;        // 0..15 -> m
    const int m0 = blockIdx.y * 64;
    const int n0 = blockIdx.x * 64;

    // load indices
    const int lam = tid >> 2;             // 0..63   A row within tile
    const int lak = (tid & 3) << 2;       // 0,4,8,12
    const int lwk = tid >> 4;             // 0..15   W k within tile
    const int lwn = (tid & 15) << 2;      // 0..60

    float acc[4][4];
#pragma unroll
    for (int i = 0; i < 4; ++i)
#pragma unroll
        for (int j = 0; j < 4; ++j) acc[i][j] = 0.0f;

    for (int k0 = 0; k0 < K; k0 += 16) {
        // stage A tile (64 x 16) as float4
        const float4 av = *reinterpret_cast<const float4*>(
            A + (size_t)(m0 + lam) * K + k0 + lak);
        sA[lak + 0][lam] = av.x;
        sA[lak + 1][lam] = av.y;
        sA[lak + 2][lam] = av.z;
        sA[lak + 3][lam] = av.w;
        // stage W tile (16 x 64) as float4
        const float4 wv = *reinterpret_cast<const float4*>(
            W + (size_t)(k0 + lwk) * N + n0 + lwn);
        sB[lwk][lwn + 0] = wv.x;
        sB[lwk][lwn + 1] = wv.y;
        sB[lwk][lwn + 2] = wv.z;
        sB[lwk][lwn + 3] = wv.w;
        __syncthreads();
#pragma unroll
        for (int k = 0; k < 16; ++k) {
            float a0 = sA[k][ty * 4 + 0];
            float a1 = sA[k][ty * 4 + 1];
            float a2 = sA[k][ty * 4 + 2];
            float a3 = sA[k][ty * 4 + 3];
            float b0 = sB[k][tx * 4 + 0];
            float b1 = sB[k][tx * 4 + 1];
            float b2 = sB[k][tx * 4 + 2];
            float b3 = sB[k][tx * 4 + 3];
            acc[0][0] += a0 * b0; acc[0][1] += a0 * b1; acc[0][2] += a0 * b2; acc[0][3] += a0 * b3;
            acc[1][0] += a1 * b0; acc[1][1] += a1 * b1; acc[1][2] += a1 * b2; acc[1][3] += a1 * b3;
            acc[2][0] += a2 * b0; acc[2][1] += a2 * b1; acc[2][2] += a2 * b2; acc[2][3] += a2 * b3;
            acc[3][0] += a3 * b0; acc[3][1] += a3 * b1; acc[3][2] += a3 * b2; acc[3][3] += a3 * b3;
        }
        __syncthreads();
    }

#pragma unroll
    for (int j = 0; j < 4; ++j) {
        int col = n0 + tx * 4 + j;
        float bv = bias[col];
#pragma unroll
        for (int i = 0; i < 4; ++i) {
            int row = m0 + ty * 4 + i;
            float v = acc[i][j] + bv;
            if (RELU) v = fmaxf(v, 0.0f);
            C[(size_t)row * N + col] = v;
        }
    }
}

// ---------------- causal attention (one block per (b,h,q)) ----------------
// q,k,v: [BS, QN] f32, column = h*HD + d.  o may alias q (each block touches
// only its own (b,q,h) 64-wide slice of q and o).
__global__ __launch_bounds__(256) void attention_kernel(
        const float* __restrict__ q, const float* __restrict__ k,
        const float* __restrict__ v, float* __restrict__ o) {
    const int qpos = blockIdx.x;
    const int hh = blockIdx.y;
    const int b = blockIdx.z;
    const int tid = threadIdx.x;

    __shared__ float qrow[HDIM];
    __shared__ float sc[SS];
    __shared__ float red[256];

    const size_t rowoff = ((size_t)(b * SS + qpos)) * QN + hh * HDIM;
    if (tid < HDIM) qrow[tid] = q[rowoff + tid];
    __syncthreads();

    const int nk = qpos + 1;
    for (int kk = tid; kk < nk; kk += 256) {
        const float* kr = k + ((size_t)(b * SS + kk)) * QN + hh * HDIM;
        float s = 0.0f;
#pragma unroll
        for (int d = 0; d < HDIM; ++d) s += qrow[d] * kr[d];
        sc[kk] = s * 0.125f;   // 1/sqrt(64)
    }
    __syncthreads();

    // block max
    float m = -3.4e38f;
    for (int kk = tid; kk < nk; kk += 256) m = fmaxf(m, sc[kk]);
    red[tid] = m;
    __syncthreads();
    for (int off = 128; off > 0; off >>= 1) {
        if (tid < off) red[tid] = fmaxf(red[tid], red[tid + off]);
        __syncthreads();
    }
    m = red[0];
    __syncthreads();

    // exp + sum
    float lsum = 0.0f;
    for (int kk = tid; kk < nk; kk += 256) {
        float e = expf(sc[kk] - m);
        sc[kk] = e;
        lsum += e;
    }
    red[tid] = lsum;
    __syncthreads();
    for (int off = 128; off > 0; off >>= 1) {
        if (tid < off) red[tid] += red[tid + off];
        __syncthreads();
    }
    const float inv = 1.0f / red[0];
    __syncthreads();

    // o[d] = sum_k p_k * v[k,d]; thread (c,d) with c = tid>>6 strides k by 4
    const int d = tid & 63;
    const int c = tid >> 6;
    float accv = 0.0f;
    for (int kk = c; kk < nk; kk += 4) {
        accv += sc[kk] * v[((size_t)(b * SS + kk)) * QN + hh * HDIM + d];
    }
    red[tid] = accv;
    __syncthreads();
    if (tid < 64) {
        float r = red[tid] + red[tid + 64] + red[tid + 128] + red[tid + 192];
        o[rowoff + tid] = r * inv;
    }
}

// ---------------- residual add + layernorm (in place on h) ----------------
__global__ __launch_bounds__(256) void add_ln_kernel(
        float* __restrict__ h, const float* __restrict__ delta,
        const float* __restrict__ sc, const float* __restrict__ bi) {
    const int t = blockIdx.x;
    const int d = threadIdx.x;
    __shared__ float red[256];
    const size_t idx = (size_t)t * DD + d;
    float val = h[idx] + delta[idx];
    red[d] = val;
    __syncthreads();
    for (int off = 128; off > 0; off >>= 1) {
        if (d < off) red[d] += red[d + off];
        __syncthreads();
    }
    float mean = red[0] * (1.0f / DD);
    __syncthreads();
    float dv = val - mean;
    red[d] = dv * dv;
    __syncthreads();
    for (int off = 128; off > 0; off >>= 1) {
        if (d < off) red[d] += red[d + off];
        __syncthreads();
    }
    float inv = rsqrtf(red[0] * (1.0f / DD) + 1e-5f);
    h[idx] = dv * inv * sc[d] + bi[d];
}

// ---------------- launch ----------------
extern "C" void kernel_launch(void* const* d_in, const int* in_sizes, int n_in,
                              void* d_out, int out_size, void* d_ws, size_t ws_size,
                              hipStream_t stream) {
    (void)in_sizes; (void)n_in; (void)out_size; (void)ws_size;

    const int*   x    = (const int*)d_in[0];
    const float* emb  = (const float*)d_in[1];
    const float* wq   = (const float*)d_in[2];
    const float* bq   = (const float*)d_in[3];
    const float* wk   = (const float*)d_in[4];
    const float* bk   = (const float*)d_in[5];
    const float* wv   = (const float*)d_in[6];
    const float* bv   = (const float*)d_in[7];
    const float* wo   = (const float*)d_in[8];
    const float* bo   = (const float*)d_in[9];
    const float* ln1s = (const float*)d_in[10];
    const float* ln1b = (const float*)d_in[11];
    const float* w1   = (const float*)d_in[12];
    const float* b1   = (const float*)d_in[13];
    const float* w2   = (const float*)d_in[14];
    const float* b2   = (const float*)d_in[15];
    const float* ln2s = (const float*)d_in[16];
    const float* ln2b = (const float*)d_in[17];
    const float* ow   = (const float*)d_in[18];
    const float* ob   = (const float*)d_in[19];

    // workspace layout (floats): h | q(=o) | k | v | t2 ; ffh aliases k+v
    // total = (BS*D)*2 + (BS*QN)*3 floats = 128 MiB
    float* h    = (float*)d_ws;                 // BS*D
    float* qb   = h + (size_t)BS * DD;          // BS*QN
    float* kb   = qb + (size_t)BS * QN;         // BS*QN
    float* vb   = kb + (size_t)BS * QN;         // BS*QN
    float* t2   = vb + (size_t)BS * QN;         // BS*D
    float* ob_  = qb;                           // attention out aliases q
    float* ffh  = kb;                           // FFN hidden aliases k+v (BS*FF floats exactly)

    embed_pe_kernel<<<BS, 256, 0, stream>>>(x, emb, h);

    for (int i = 0; i < NLAYER; ++i) {
        const float* wqi = wq + (size_t)i * DD * QN;
        const float* wki = wk + (size_t)i * DD * QN;
        const float* wvi = wv + (size_t)i * DD * QN;
        const float* woi = wo + (size_t)i * QN * DD;
        const float* w1i = w1 + (size_t)i * DD * FFD;
        const float* w2i = w2 + (size_t)i * FFD * DD;

        dim3 gq(QN / 64, BS / 64);
        gemm64_kernel<false><<<gq, 256, 0, stream>>>(h, wqi, bq + i * QN, qb, BS, QN, DD);
        gemm64_kernel<false><<<gq, 256, 0, stream>>>(h, wki, bk + i * QN, kb, BS, QN, DD);
        gemm64_kernel<false><<<gq, 256, 0, stream>>>(h, wvi, bv + i * QN, vb, BS, QN, DD);

        attention_kernel<<<dim3(SS, HH, BB), 256, 0, stream>>>(qb, kb, vb, ob_);

        gemm64_kernel<false><<<dim3(DD / 64, BS / 64), 256, 0, stream>>>(
            ob_, woi, bo + i * DD, t2, BS, DD, QN);
        add_ln_kernel<<<BS, 256, 0, stream>>>(h, t2, ln1s + i * DD, ln1b + i * DD);

        gemm64_kernel<true><<<dim3(FFD / 64, BS / 64), 256, 0, stream>>>(
            h, w1i, b1 + i * FFD, ffh, BS, FFD, DD);
        gemm64_kernel<false><<<dim3(DD / 64, BS / 64), 256, 0, stream>>>(
            ffh, w2i, b2 + i * DD, t2, BS, DD, FFD);
        add_ln_kernel<<<BS, 256, 0, stream>>>(h, t2, ln2s + i * DD, ln2b + i * DD);
    }

    gemm64_kernel<false><<<dim3(OUTD / 64, BS / 64), 256, 0, stream>>>(
        h, ow, ob, (float*)d_out, BS, OUTD, DD);
}

// Round 3
// 7503.262 us; speedup vs baseline: 2.8650x; 2.8650x over previous
//
#include <hip/hip_runtime.h>

// ---------------- problem constants ----------------
#define BB   32
#define SS   512
#define DD   256
#define HH   8
#define HDIM 64
#define NLAYER 5
#define FFD  1024
#define OUTD 4096
#define QN   512            // H*HD
#define BS   (BB*SS)        // 16384 tokens

// ---------------- embedding + positional encoding ----------------
__global__ __launch_bounds__(256) void embed_pe_kernel(
        const int* __restrict__ x, const float* __restrict__ emb,
        float* __restrict__ h) {
    int t = blockIdx.x;
    int d = threadIdx.x;
    int pos = t % SS;
    int tok = x[t];
    float e = emb[(size_t)tok * DD + d];
    float expo = -(float)(d & ~1) / (float)DD;
    float ang = (float)pos * powf(10000.0f, expo);
    float pe = (d & 1) ? cosf(ang) : sinf(ang);
    h[(size_t)t * DD + d] = e + pe;
}

// ---------------- generic tiled GEMM (f32 SIMT) ----------------
template<bool RELU>
__global__ __launch_bounds__(256) void gemm64_kernel(
        const float* __restrict__ A, const float* __restrict__ W,
        const float* __restrict__ bias, float* __restrict__ C,
        int M, int N, int K) {
    __shared__ float sA[16][65];
    __shared__ float sB[16][68];

    const int tid = threadIdx.x;
    const int tx = tid & 15;
    const int ty = tid >> 4;
    const int m0 = blockIdx.y * 64;
    const int n0 = blockIdx.x * 64;

    const int lam = tid >> 2;
    const int lak = (tid & 3) << 2;
    const int lwk = tid >> 4;
    const int lwn = (tid & 15) << 2;

    float acc[4][4];
#pragma unroll
    for (int i = 0; i < 4; ++i)
#pragma unroll
        for (int j = 0; j < 4; ++j) acc[i][j] = 0.0f;

    for (int k0 = 0; k0 < K; k0 += 16) {
        const float4 av = *reinterpret_cast<const float4*>(
            A + (size_t)(m0 + lam) * K + k0 + lak);
        sA[lak + 0][lam] = av.x;
        sA[lak + 1][lam] = av.y;
        sA[lak + 2][lam] = av.z;
        sA[lak + 3][lam] = av.w;
        const float4 wv = *reinterpret_cast<const float4*>(
            W + (size_t)(k0 + lwk) * N + n0 + lwn);
        sB[lwk][lwn + 0] = wv.x;
        sB[lwk][lwn + 1] = wv.y;
        sB[lwk][lwn + 2] = wv.z;
        sB[lwk][lwn + 3] = wv.w;
        __syncthreads();
#pragma unroll
        for (int k = 0; k < 16; ++k) {
            float a0 = sA[k][ty * 4 + 0];
            float a1 = sA[k][ty * 4 + 1];
            float a2 = sA[k][ty * 4 + 2];
            float a3 = sA[k][ty * 4 + 3];
            float b0 = sB[k][tx * 4 + 0];
            float b1 = sB[k][tx * 4 + 1];
            float b2 = sB[k][tx * 4 + 2];
            float b3 = sB[k][tx * 4 + 3];
            acc[0][0] += a0 * b0; acc[0][1] += a0 * b1; acc[0][2] += a0 * b2; acc[0][3] += a0 * b3;
            acc[1][0] += a1 * b0; acc[1][1] += a1 * b1; acc[1][2] += a1 * b2; acc[1][3] += a1 * b3;
            acc[2][0] += a2 * b0; acc[2][1] += a2 * b1; acc[2][2] += a2 * b2; acc[2][3] += a2 * b3;
            acc[3][0] += a3 * b0; acc[3][1] += a3 * b1; acc[3][2] += a3 * b2; acc[3][3] += a3 * b3;
        }
        __syncthreads();
    }

#pragma unroll
    for (int j = 0; j < 4; ++j) {
        int col = n0 + tx * 4 + j;
        float bv = bias[col];
#pragma unroll
        for (int i = 0; i < 4; ++i) {
            int row = m0 + ty * 4 + i;
            float v = acc[i][j] + bv;
            if (RELU) v = fmaxf(v, 0.0f);
            C[(size_t)row * N + col] = v;
        }
    }
}

// ---------------- flash attention ----------------
// One block per (q-tile of 64, head, batch). q,k,v,o: [BS, QN], col = h*64+d.
// o aliases q safely: each block reads only its own Q tile (staged first) and
// writes only that same region.
__global__ __launch_bounds__(256) void flash_attn_kernel(
        const float* __restrict__ q, const float* __restrict__ k,
        const float* __restrict__ v, float* __restrict__ o) {
    const int qt  = blockIdx.x;   // 0..7
    const int hh  = blockIdx.y;   // 0..7
    const int b   = blockIdx.z;   // 0..31
    const int tid = threadIdx.x;
    const int tx  = tid & 15;     // score-col / out-col group
    const int ty  = tid >> 4;     // row group

    __shared__ float Qs[64][68];
    __shared__ float Ks[64][68];
    __shared__ float Vs[64][68];
    __shared__ float Ps[64][68];
    __shared__ float mrow[64], lrow[64], arow[64];

    const size_t qbase = ((size_t)(b * SS + qt * 64)) * QN + hh * HDIM;

    // load Q tile (64x64), pre-scaled by 1/sqrt(HD)=0.125
#pragma unroll
    for (int it = 0; it < 4; ++it) {
        int idx = tid + it * 256;          // 0..1023
        int row = idx >> 4, c4 = (idx & 15) * 4;
        float4 qv = *reinterpret_cast<const float4*>(q + qbase + (size_t)row * QN + c4);
        Qs[row][c4 + 0] = qv.x * 0.125f;
        Qs[row][c4 + 1] = qv.y * 0.125f;
        Qs[row][c4 + 2] = qv.z * 0.125f;
        Qs[row][c4 + 3] = qv.w * 0.125f;
    }
    if (tid < 64) { mrow[tid] = -3.4e38f; lrow[tid] = 0.0f; }

    float o_acc[4][4];
#pragma unroll
    for (int i = 0; i < 4; ++i)
#pragma unroll
        for (int j = 0; j < 4; ++j) o_acc[i][j] = 0.0f;

    for (int kt = 0; kt <= qt; ++kt) {
        __syncthreads();   // previous tile's Ks/Vs/Ps fully consumed
        const size_t kbase = ((size_t)(b * SS + kt * 64)) * QN + hh * HDIM;
#pragma unroll
        for (int it = 0; it < 4; ++it) {
            int idx = tid + it * 256;
            int row = idx >> 4, c4 = (idx & 15) * 4;
            float4 kv = *reinterpret_cast<const float4*>(k + kbase + (size_t)row * QN + c4);
            Ks[row][c4 + 0] = kv.x; Ks[row][c4 + 1] = kv.y;
            Ks[row][c4 + 2] = kv.z; Ks[row][c4 + 3] = kv.w;
            float4 vv = *reinterpret_cast<const float4*>(v + kbase + (size_t)row * QN + c4);
            Vs[row][c4 + 0] = vv.x; Vs[row][c4 + 1] = vv.y;
            Vs[row][c4 + 2] = vv.z; Vs[row][c4 + 3] = vv.w;
        }
        __syncthreads();

        // S = Q·K^T : thread computes rows ty*4.., score-cols tx*4..
        float s[4][4];
#pragma unroll
        for (int i = 0; i < 4; ++i)
#pragma unroll
            for (int j = 0; j < 4; ++j) s[i][j] = 0.0f;

#pragma unroll 4
        for (int d4 = 0; d4 < 16; ++d4) {
            float4 qv0 = *reinterpret_cast<const float4*>(&Qs[ty * 4 + 0][d4 * 4]);
            float4 qv1 = *reinterpret_cast<const float4*>(&Qs[ty * 4 + 1][d4 * 4]);
            float4 qv2 = *reinterpret_cast<const float4*>(&Qs[ty * 4 + 2][d4 * 4]);
            float4 qv3 = *reinterpret_cast<const float4*>(&Qs[ty * 4 + 3][d4 * 4]);
            float4 kv0 = *reinterpret_cast<const float4*>(&Ks[tx * 4 + 0][d4 * 4]);
            float4 kv1 = *reinterpret_cast<const float4*>(&Ks[tx * 4 + 1][d4 * 4]);
            float4 kv2 = *reinterpret_cast<const float4*>(&Ks[tx * 4 + 2][d4 * 4]);
            float4 kv3 = *reinterpret_cast<const float4*>(&Ks[tx * 4 + 3][d4 * 4]);
#define DOT4(a, c) (a.x*c.x + a.y*c.y + a.z*c.z + a.w*c.w)
            s[0][0] += DOT4(qv0, kv0); s[0][1] += DOT4(qv0, kv1); s[0][2] += DOT4(qv0, kv2); s[0][3] += DOT4(qv0, kv3);
            s[1][0] += DOT4(qv1, kv0); s[1][1] += DOT4(qv1, kv1); s[1][2] += DOT4(qv1, kv2); s[1][3] += DOT4(qv1, kv3);
            s[2][0] += DOT4(qv2, kv0); s[2][1] += DOT4(qv2, kv1); s[2][2] += DOT4(qv2, kv2); s[2][3] += DOT4(qv2, kv3);
            s[3][0] += DOT4(qv3, kv0); s[3][1] += DOT4(qv3, kv1); s[3][2] += DOT4(qv3, kv2); s[3][3] += DOT4(qv3, kv3);
#undef DOT4
        }
#pragma unroll
        for (int i = 0; i < 4; ++i) {
            float4 sv = make_float4(s[i][0], s[i][1], s[i][2], s[i][3]);
            *reinterpret_cast<float4*>(&Ps[ty * 4 + i][tx * 4]) = sv;
        }
        __syncthreads();

        // online-softmax row scan (wave 0; skewed column order vs bank stride)
        if (tid < 64) {
            const int lim = (kt == qt) ? (tid + 1) : 64;
            float mo = mrow[tid];
            float mt = mo;
            for (int j0 = 0; j0 < 64; ++j0) {
                int j = (j0 + tid) & 63;
                float val = Ps[tid][j];
                if (j < lim) mt = fmaxf(mt, val);
            }
            float alpha = __expf(mo - mt);
            float sum = 0.0f;
            for (int j0 = 0; j0 < 64; ++j0) {
                int j = (j0 + tid) & 63;
                float p = (j < lim) ? __expf(Ps[tid][j] - mt) : 0.0f;
                Ps[tid][j] = p;
                sum += p;
            }
            mrow[tid] = mt;
            lrow[tid] = lrow[tid] * alpha + sum;
            arow[tid] = alpha;
        }
        __syncthreads();

        // O = O*alpha + P·V : thread rows ty*4.., out-cols tx*4..
        float al0 = arow[ty * 4 + 0], al1 = arow[ty * 4 + 1];
        float al2 = arow[ty * 4 + 2], al3 = arow[ty * 4 + 3];
#pragma unroll
        for (int j = 0; j < 4; ++j) {
            o_acc[0][j] *= al0; o_acc[1][j] *= al1;
            o_acc[2][j] *= al2; o_acc[3][j] *= al3;
        }
#pragma unroll 4
        for (int k4 = 0; k4 < 16; ++k4) {
            float4 p0 = *reinterpret_cast<const float4*>(&Ps[ty * 4 + 0][k4 * 4]);
            float4 p1 = *reinterpret_cast<const float4*>(&Ps[ty * 4 + 1][k4 * 4]);
            float4 p2 = *reinterpret_cast<const float4*>(&Ps[ty * 4 + 2][k4 * 4]);
            float4 p3 = *reinterpret_cast<const float4*>(&Ps[ty * 4 + 3][k4 * 4]);
#pragma unroll
            for (int kk = 0; kk < 4; ++kk) {
                float4 vv = *reinterpret_cast<const float4*>(&Vs[k4 * 4 + kk][tx * 4]);
                float pa = (kk == 0) ? p0.x : (kk == 1) ? p0.y : (kk == 2) ? p0.z : p0.w;
                float pb = (kk == 0) ? p1.x : (kk == 1) ? p1.y : (kk == 2) ? p1.z : p1.w;
                float pc = (kk == 0) ? p2.x : (kk == 1) ? p2.y : (kk == 2) ? p2.z : p2.w;
                float pd = (kk == 0) ? p3.x : (kk == 1) ? p3.y : (kk == 2) ? p3.z : p3.w;
                o_acc[0][0] += pa * vv.x; o_acc[0][1] += pa * vv.y; o_acc[0][2] += pa * vv.z; o_acc[0][3] += pa * vv.w;
                o_acc[1][0] += pb * vv.x; o_acc[1][1] += pb * vv.y; o_acc[1][2] += pb * vv.z; o_acc[1][3] += pb * vv.w;
                o_acc[2][0] += pc * vv.x; o_acc[2][1] += pc * vv.y; o_acc[2][2] += pc * vv.z; o_acc[2][3] += pc * vv.w;
                o_acc[3][0] += pd * vv.x; o_acc[3][1] += pd * vv.y; o_acc[3][2] += pd * vv.z; o_acc[3][3] += pd * vv.w;
            }
        }
    }

    // write O / l
#pragma unroll
    for (int i = 0; i < 4; ++i) {
        int row = ty * 4 + i;
        float invl = 1.0f / lrow[row];
        float4 ov = make_float4(o_acc[i][0] * invl, o_acc[i][1] * invl,
                                o_acc[i][2] * invl, o_acc[i][3] * invl);
        *reinterpret_cast<float4*>(o + qbase + (size_t)row * QN + tx * 4) = ov;
    }
}

// ---------------- residual add + layernorm (in place on h) ----------------
__global__ __launch_bounds__(256) void add_ln_kernel(
        float* __restrict__ h, const float* __restrict__ delta,
        const float* __restrict__ sc, const float* __restrict__ bi) {
    const int t = blockIdx.x;
    const int d = threadIdx.x;
    __shared__ float red[256];
    const size_t idx = (size_t)t * DD + d;
    float val = h[idx] + delta[idx];
    red[d] = val;
    __syncthreads();
    for (int off = 128; off > 0; off >>= 1) {
        if (d < off) red[d] += red[d + off];
        __syncthreads();
    }
    float mean = red[0] * (1.0f / DD);
    __syncthreads();
    float dv = val - mean;
    red[d] = dv * dv;
    __syncthreads();
    for (int off = 128; off > 0; off >>= 1) {
        if (d < off) red[d] += red[d + off];
        __syncthreads();
    }
    float inv = rsqrtf(red[0] * (1.0f / DD) + 1e-5f);
    h[idx] = dv * inv * sc[d] + bi[d];
}

// ---------------- launch ----------------
extern "C" void kernel_launch(void* const* d_in, const int* in_sizes, int n_in,
                              void* d_out, int out_size, void* d_ws, size_t ws_size,
                              hipStream_t stream) {
    (void)in_sizes; (void)n_in; (void)out_size; (void)ws_size;

    const int*   x    = (const int*)d_in[0];
    const float* emb  = (const float*)d_in[1];
    const float* wq   = (const float*)d_in[2];
    const float* bq   = (const float*)d_in[3];
    const float* wk   = (const float*)d_in[4];
    const float* bk   = (const float*)d_in[5];
    const float* wv   = (const float*)d_in[6];
    const float* bv   = (const float*)d_in[7];
    const float* wo   = (const float*)d_in[8];
    const float* bo   = (const float*)d_in[9];
    const float* ln1s = (const float*)d_in[10];
    const float* ln1b = (const float*)d_in[11];
    const float* w1   = (const float*)d_in[12];
    const float* b1   = (const float*)d_in[13];
    const float* w2   = (const float*)d_in[14];
    const float* b2   = (const float*)d_in[15];
    const float* ln2s = (const float*)d_in[16];
    const float* ln2b = (const float*)d_in[17];
    const float* ow   = (const float*)d_in[18];
    const float* ob   = (const float*)d_in[19];

    float* h    = (float*)d_ws;                 // BS*D
    float* qb   = h + (size_t)BS * DD;          // BS*QN
    float* kb   = qb + (size_t)BS * QN;         // BS*QN
    float* vb   = kb + (size_t)BS * QN;         // BS*QN
    float* t2   = vb + (size_t)BS * QN;         // BS*D
    float* ob_  = qb;                           // attention out aliases q
    float* ffh  = kb;                           // FFN hidden aliases k+v

    embed_pe_kernel<<<BS, 256, 0, stream>>>(x, emb, h);

    for (int i = 0; i < NLAYER; ++i) {
        const float* wqi = wq + (size_t)i * DD * QN;
        const float* wki = wk + (size_t)i * DD * QN;
        const float* wvi = wv + (size_t)i * DD * QN;
        const float* woi = wo + (size_t)i * QN * DD;
        const float* w1i = w1 + (size_t)i * DD * FFD;
        const float* w2i = w2 + (size_t)i * FFD * DD;

        dim3 gq(QN / 64, BS / 64);
        gemm64_kernel<false><<<gq, 256, 0, stream>>>(h, wqi, bq + i * QN, qb, BS, QN, DD);
        gemm64_kernel<false><<<gq, 256, 0, stream>>>(h, wki, bk + i * QN, kb, BS, QN, DD);
        gemm64_kernel<false><<<gq, 256, 0, stream>>>(h, wvi, bv + i * QN, vb, BS, QN, DD);

        flash_attn_kernel<<<dim3(SS / 64, HH, BB), 256, 0, stream>>>(qb, kb, vb, ob_);

        gemm64_kernel<false><<<dim3(DD / 64, BS / 64), 256, 0, stream>>>(
            ob_, woi, bo + i * DD, t2, BS, DD, QN);
        add_ln_kernel<<<BS, 256, 0, stream>>>(h, t2, ln1s + i * DD, ln1b + i * DD);

        gemm64_kernel<true><<<dim3(FFD / 64, BS / 64), 256, 0, stream>>>(
            h, w1i, b1 + i * FFD, ffh, BS, FFD, DD);
        gemm64_kernel<false><<<dim3(DD / 64, BS / 64), 256, 0, stream>>>(
            ffh, w2i, b2 + i * DD, t2, BS, DD, FFD);
        add_ln_kernel<<<BS, 256, 0, stream>>>(h, t2, ln2s + i * DD, ln2b + i * DD);
    }

    gemm64_kernel<false><<<dim3(OUTD / 64, BS / 64), 256, 0, stream>>>(
        h, ow, ob, (float*)d_out, BS, OUTD, DD);
}